// Round 4
// baseline (384.736 us; speedup 1.0000x reference)
//
#include <hip/hip_runtime.h>

// Problem constants (match reference)
#define N_   8
#define C_   256
#define H_   128
#define W_   128
#define HW_  16384
#define NB_  20
constexpr float TEMP  = 0.5f;
constexpr float IMG_W = 800.0f;
constexpr float IMG_H = 800.0f;

using f4 = __attribute__((ext_vector_type(4))) float;

__device__ __forceinline__ float waveReduceSum(float v) {
    v += __shfl_xor(v, 32, 64);
    v += __shfl_xor(v, 16, 64);
    v += __shfl_xor(v, 8, 64);
    v += __shfl_xor(v, 4, 64);
    v += __shfl_xor(v, 2, 64);
    v += __shfl_xor(v, 1, 64);
    return v;
}

// K1: single pass over pT (round-2 proven form: 4-row batched fold, 7 shuffles
// per 4 rows, VGPR ~44). No global atomics. grid: 2048 blocks x 256 threads.
__global__ __launch_bounds__(256, 4) void k_stats(const float* __restrict__ pT,
                                                  float* __restrict__ chan_part,
                                                  float* __restrict__ fea_sum,
                                                  float* __restrict__ smax_part) {
    const int n     = blockIdx.x & 7;
    const int chunk = blockIdx.x >> 3;        // 0..255
    const int wave  = threadIdx.x >> 6;
    const int lane  = threadIdx.x & 63;
    const int hw0   = chunk * 64 + wave * 16; // wave's 16 rows

    float4 cacc = make_float4(0.f, 0.f, 0.f, 0.f);
    float vmax = 0.f;
    #pragma unroll
    for (int g = 0; g < 4; ++g) {
        const int r = hw0 + g * 4;
        float p[4];
        #pragma unroll
        for (int j = 0; j < 4; ++j) {
            const float4 v = *(const float4*)(pT + ((size_t)((r + j) * N_ + n)) * C_ + lane * 4);
            const float ax = fabsf(v.x), ay = fabsf(v.y), az = fabsf(v.z), aw = fabsf(v.w);
            cacc.x += ax; cacc.y += ay; cacc.z += az; cacc.w += aw;
            p[j] = ax + ay + az + aw;
        }
        float a01 = (lane & 32) ? p[1] : p[0];
        float b01 = (lane & 32) ? p[0] : p[1];
        const float u01 = a01 + __shfl_xor(b01, 32, 64);
        float a23 = (lane & 32) ? p[3] : p[2];
        float b23 = (lane & 32) ? p[2] : p[3];
        const float u23 = a23 + __shfl_xor(b23, 32, 64);
        float aq = (lane & 16) ? u23 : u01;
        float bq = (lane & 16) ? u01 : u23;
        float u = aq + __shfl_xor(bq, 16, 64);
        u += __shfl_xor(u, 8, 64);
        u += __shfl_xor(u, 4, 64);
        u += __shfl_xor(u, 2, 64);
        u += __shfl_xor(u, 1, 64);
        // quadrant q = lane>>4 holds rowsum of row r + rowmap(q); rowmap: q0->0,q1->2,q2->1,q3->3
        vmax = fmaxf(vmax, u);
        if ((lane & 15) == 0) {
            const int q = lane >> 4;
            const int row = ((q & 1) << 1) | (q >> 1);
            fea_sum[n * HW_ + r + row] = u;
        }
    }
    vmax = fmaxf(vmax, __shfl_xor(vmax, 16, 64));
    vmax = fmaxf(vmax, __shfl_xor(vmax, 32, 64));

    __shared__ float lds[4][C_];
    __shared__ float wmax[4];
    if (lane == 0) wmax[wave] = vmax;
    ((float4*)lds[wave])[lane] = cacc;
    __syncthreads();
    const int c = threadIdx.x;
    chan_part[((size_t)(n * 256 + chunk)) * C_ + c] =
        lds[0][c] + lds[1][c] + lds[2][c] + lds[3][c];
    if (threadIdx.x == 0)
        smax_part[n * 256 + chunk] =
            fmaxf(fmaxf(wmax[0], wmax[1]), fmaxf(wmax[2], wmax[3]));
}

// K2 (fused prep): 64 blocks = (n, sub). Each block independently computes the
// FULL spatial max, FULL sden, and FULL bg count for its n (deterministic,
// identical across the 8 blocks of one n — redundant compute is ~2us, cheaper
// than a dispatch + cross-block handoff). Then writes A_t[hw][n] for its own
// 2048 rows. sub==0 blocks also combine channel partials -> B[n,c]=sqrt(C_att).
__global__ __launch_bounds__(256) void k_prep(const float* __restrict__ fea_sum,
                                              const float* __restrict__ chan_part,
                                              const float* __restrict__ smax_part,
                                              const float* __restrict__ gt,
                                              float* __restrict__ A_t,   // [HW][8]
                                              float* __restrict__ B) {
    const int n   = blockIdx.x >> 3;
    const int sub = blockIdx.x & 7;
    const int tid = threadIdx.x;
    __shared__ float red[256];
    __shared__ int   bb[NB_][4];     // wmin, wmax, hmin, hmax
    __shared__ float barea[NB_];

    if (tid < NB_) {
        const float* bx = gt + ((size_t)n * NB_ + tid) * 4;
        const int wmin = (int)floorf(bx[0] / IMG_W * (float)W_);
        const int wmax = (int)ceilf (bx[2] / IMG_W * (float)W_);
        const int hmin = (int)floorf(bx[1] / IMG_H * (float)H_);
        const int hmax = (int)ceilf (bx[3] / IMG_H * (float)H_);
        bb[tid][0] = wmin; bb[tid][1] = wmax; bb[tid][2] = hmin; bb[tid][3] = hmax;
        barea[tid] = 1.0f / (float)(hmax + 1 - hmin) / (float)(wmax + 1 - wmin);
    }

    // ---- spatial max over 256 chunk maxes
    red[tid] = smax_part[n * 256 + tid];
    __syncthreads();
    for (int s = 128; s > 0; s >>= 1) { if (tid < s) red[tid] = fmaxf(red[tid], red[tid + s]); __syncthreads(); }
    const float sm = red[0] * (1.0f / (C_ * TEMP));
    __syncthreads();

    // ---- full sden (identical order in every block of this n)
    float acc = 0.f;
    for (int i = tid; i < HW_; i += 256)
        acc += expf(fea_sum[n * HW_ + i] * (1.0f / (C_ * TEMP)) - sm);
    red[tid] = acc; __syncthreads();
    for (int s = 128; s > 0; s >>= 1) { if (tid < s) red[tid] += red[tid + s]; __syncthreads(); }
    const float sden = red[0];
    __syncthreads();

    // ---- full bg count (predicate only; fg==0 <=> inside no box)
    float cnt = 0.f;
    for (int i = tid; i < HW_; i += 256) {
        const int h = i >> 7, w = i & 127;
        bool in = false;
        for (int b = 0; b < NB_; ++b)
            in = in || (h >= bb[b][2] && h <= bb[b][3] && w >= bb[b][0] && w <= bb[b][1]);
        cnt += in ? 0.f : 1.f;
    }
    red[tid] = cnt; __syncthreads();
    for (int s = 128; s > 0; s >>= 1) { if (tid < s) red[tid] += red[tid + s]; __syncthreads(); }
    const float bgs = red[0];
    const float bginv = (bgs > 0.f) ? 1.0f / bgs : 1.0f;
    __syncthreads();

    // ---- A for own rows [sub*2048, +2048), stored transposed: A_t[hw*8 + n]
    for (int k = 0; k < 8; ++k) {
        const int i = sub * 2048 + k * 256 + tid;
        const int h = i >> 7, w = i & 127;
        float fg = 0.f;
        for (int b = 0; b < NB_; ++b)
            if (h >= bb[b][2] && h <= bb[b][3] && w >= bb[b][0] && w <= bb[b][1])
                fg = fmaxf(fg, barea[b]);
        const float S_att = (float)HW_ * expf(fea_sum[n * HW_ + i] * (1.0f / (C_ * TEMP)) - sm) / sden;
        const float bg = (fg <= 0.f) ? bginv : 0.f;
        A_t[(size_t)i * 8 + n] = sqrtf(S_att) * (sqrtf(fg) + sqrtf(bg)) * (1.0f / (float)HW_);
    }

    if (sub != 0) return;   // block-uniform exit
    __syncthreads();

    // ---- channel combine + softmax -> B
    float cs = 0.f;
    #pragma unroll 4
    for (int k2 = 0; k2 < 256; ++k2)
        cs += chan_part[((size_t)(n * 256 + k2)) * C_ + tid];
    const float lc = cs * (1.0f / (HW_ * TEMP));
    red[tid] = lc; __syncthreads();
    for (int s = 128; s > 0; s >>= 1) { if (tid < s) red[tid] = fmaxf(red[tid], red[tid + s]); __syncthreads(); }
    const float cmax = red[0]; __syncthreads();
    const float e = expf(lc - cmax);
    red[tid] = e; __syncthreads();
    for (int s = 128; s > 0; s >>= 1) { if (tid < s) red[tid] += red[tid + s]; __syncthreads(); }
    B[n * C_ + tid] = sqrtf((float)C_ * e / red[0]);   // sqrt(C_att)
}

// K3: main weighted-L1 reduction — CONTIGUOUS tiles. Block = 32 consecutive
// (hw,n) rows = one 32 KB span per input. Wave w owns hw = bid*4+w and all 8 n
// (rows hw*8..hw*8+7 are contiguous in memory). B staged in LDS (8 KB); A_t row
// of 8 floats is one cacheline. pS loaded non-temporally (single-use; keep
// L3-resident pT hot). grid: 4096 blocks x 256 threads.
__global__ __launch_bounds__(256, 4) void k_main(const float* __restrict__ pS,
                                                 const float* __restrict__ pT,
                                                 const float* __restrict__ A_t,
                                                 const float* __restrict__ B,
                                                 float* __restrict__ partials) {
    __shared__ float4 ldsB[512];
    const int tid = threadIdx.x;
    ldsB[tid]       = ((const float4*)B)[tid];
    ldsB[tid + 256] = ((const float4*)B)[tid + 256];
    __syncthreads();

    const int wave = tid >> 6, lane = tid & 63;
    const int hw   = blockIdx.x * 4 + wave;          // 0..16383
    float a[8];
    #pragma unroll
    for (int j = 0; j < 8; ++j) a[j] = A_t[(size_t)hw * 8 + j];

    const size_t base4 = (size_t)hw * 512 + lane;    // float4 index of (row hw*8, lane)
    f4 sv[8], tv[8];
    #pragma unroll
    for (int j = 0; j < 8; ++j) {
        sv[j] = __builtin_nontemporal_load((const f4*)pS + base4 + (size_t)j * 64);
        tv[j] = *((const f4*)pT + base4 + (size_t)j * 64);
    }
    float acc = 0.f;
    #pragma unroll
    for (int j = 0; j < 8; ++j) {
        const float4 b4 = ldsB[j * 64 + lane];
        const float part = fabsf(sv[j].x - tv[j].x) * b4.x + fabsf(sv[j].y - tv[j].y) * b4.y +
                           fabsf(sv[j].z - tv[j].z) * b4.z + fabsf(sv[j].w - tv[j].w) * b4.w;
        acc += a[j] * part;
    }
    acc = waveReduceSum(acc);
    __shared__ float red[4];
    if (lane == 0) red[wave] = acc;
    __syncthreads();
    if (tid == 0) partials[blockIdx.x] = red[0] + red[1] + red[2] + red[3];
}

// K4: deterministic finalize: sum 4096 block partials -> d_out[0]
__global__ __launch_bounds__(256) void k_final(const float* __restrict__ partials,
                                               float* __restrict__ out) {
    float a = 0.f;
    for (int i = threadIdx.x; i < 4096; i += 256) a += partials[i];
    __shared__ float red[256];
    red[threadIdx.x] = a; __syncthreads();
    for (int s = 128; s > 0; s >>= 1) { if (threadIdx.x < s) red[threadIdx.x] += red[threadIdx.x + s]; __syncthreads(); }
    if (threadIdx.x == 0) out[0] = red[0];
}

extern "C" void kernel_launch(void* const* d_in, const int* in_sizes, int n_in,
                              void* d_out, int out_size, void* d_ws, size_t ws_size,
                              hipStream_t stream) {
    const float* pS = (const float*)d_in[0];
    const float* pT = (const float*)d_in[1];
    const float* gt = (const float*)d_in[2];
    float* ws = (float*)d_ws;

    // workspace layout (floats) — no atomics, no memset
    float* chan_part = ws;                        // 524288 = N*256*C
    float* smax_part = chan_part + 524288;        // 2048
    float* fea_sum   = smax_part + 2048;          // 131072
    float* A_t       = fea_sum + 131072;          // 131072 = HW*8 (transposed A)
    float* B         = A_t + 131072;              // 2048   (16B aligned)
    float* partials  = B + 2048;                  // 4096

    k_stats<<<2048, 256, 0, stream>>>(pT, chan_part, fea_sum, smax_part);
    k_prep <<<64,   256, 0, stream>>>(fea_sum, chan_part, smax_part, gt, A_t, B);
    k_main <<<4096, 256, 0, stream>>>(pS, pT, A_t, B, partials);
    k_final<<<1,    256, 0, stream>>>(partials, (float*)d_out);
}

// Round 5
// 319.604 us; speedup vs baseline: 1.2038x; 1.2038x over previous
//
#include <hip/hip_runtime.h>

// Problem constants (match reference)
#define N_   8
#define C_   256
#define H_   128
#define W_   128
#define HW_  16384
#define NB_  20
constexpr float TEMP  = 0.5f;
constexpr float IMG_W = 800.0f;
constexpr float IMG_H = 800.0f;

using f4 = __attribute__((ext_vector_type(4))) float;

__device__ __forceinline__ float waveReduceSum(float v) {
    v += __shfl_xor(v, 32, 64);
    v += __shfl_xor(v, 16, 64);
    v += __shfl_xor(v, 8, 64);
    v += __shfl_xor(v, 4, 64);
    v += __shfl_xor(v, 2, 64);
    v += __shfl_xor(v, 1, 64);
    return v;
}

// K1: single pass over pT — CONTIGUOUS tiles (k_main round-4 lesson applied).
// Wave covers hw0,hw0+1 for ALL 8 n = 16 consecutive 1KB rows = 16KB contiguous;
// block (4 waves) covers 64KB contiguous. Per-row fold math identical to the
// verified round-2 fold (row j = (hw0 + j/8, n = j&7)), so fea_sum is bitwise
// unchanged. Channel sums: per-n register accumulators -> 32KB LDS block
// combine -> chan_part[n][bid][c] (2048 chunks/n). Spatial max: per-n via
// quadrant identity -> smax_part[n][bid]. No atomics. grid: 2048 x 256.
__global__ __launch_bounds__(256, 4) void k_stats(const float* __restrict__ pT,
                                                  float* __restrict__ chan_part,  // [N][2048][C]
                                                  float* __restrict__ fea_sum,    // [N][HW]
                                                  float* __restrict__ smax_part) {// [N][2048]
    const int bid  = blockIdx.x;
    const int wave = threadIdx.x >> 6;
    const int lane = threadIdx.x & 63;
    const int hw0  = bid * 8 + wave * 2;      // wave: hw0, hw0+1, all n
    const int row0 = hw0 * 8;                 // first of 16 consecutive rows

    float4 v[16];
    #pragma unroll
    for (int j = 0; j < 16; ++j)
        v[j] = *(const float4*)(pT + ((size_t)(row0 + j)) * C_ + lane * 4);

    float4 cacc[8];
    float p[16];
    #pragma unroll
    for (int j = 0; j < 16; ++j) {
        const float ax = fabsf(v[j].x), ay = fabsf(v[j].y), az = fabsf(v[j].z), aw = fabsf(v[j].w);
        p[j] = ax + ay + az + aw;            // same add order as all prior rounds
        const int n = j & 7;
        if (j < 8) cacc[n] = make_float4(ax, ay, az, aw);
        else { cacc[n].x += ax; cacc[n].y += ay; cacc[n].z += az; cacc[n].w += aw; }
    }

    // 4-row batched fold (verified round-2 form), groups of j = g*4..g*4+3.
    // After fold: quadrant q holds rowsum of j = g*4 + rowmap(q),
    // rowmap(q) = ((q&1)<<1)|(q>>1).  g even -> n<4 (vlo), g odd -> n>=4 (vhi).
    float vlo = 0.f, vhi = 0.f;
    #pragma unroll
    for (int g = 0; g < 4; ++g) {
        const float p0 = p[g*4+0], p1 = p[g*4+1], p2 = p[g*4+2], p3 = p[g*4+3];
        float a01 = (lane & 32) ? p1 : p0;
        float b01 = (lane & 32) ? p0 : p1;
        const float u01 = a01 + __shfl_xor(b01, 32, 64);
        float a23 = (lane & 32) ? p3 : p2;
        float b23 = (lane & 32) ? p2 : p3;
        const float u23 = a23 + __shfl_xor(b23, 32, 64);
        float aq = (lane & 16) ? u23 : u01;
        float bq = (lane & 16) ? u01 : u23;
        float u = aq + __shfl_xor(bq, 16, 64);
        u += __shfl_xor(u, 8, 64);
        u += __shfl_xor(u, 4, 64);
        u += __shfl_xor(u, 2, 64);
        u += __shfl_xor(u, 1, 64);
        if (g & 1) vhi = fmaxf(vhi, u); else vlo = fmaxf(vlo, u);
        if ((lane & 15) == 0) {
            const int q  = lane >> 4;
            const int j  = g * 4 + (((q & 1) << 1) | (q >> 1));
            fea_sum[(j & 7) * HW_ + hw0 + (j >> 3)] = u;
        }
    }

    __shared__ float ldsc[4][8][C_];     // 32 KB
    __shared__ float wmax[4][8];
    if ((lane & 15) == 0) {
        const int q   = lane >> 4;
        const int nlo = ((q & 1) << 1) | (q >> 1);
        wmax[wave][nlo]     = vlo;
        wmax[wave][nlo + 4] = vhi;
    }
    #pragma unroll
    for (int n = 0; n < 8; ++n)
        *(float4*)&ldsc[wave][n][lane * 4] = cacc[n];
    __syncthreads();
    const int tid = threadIdx.x;
    #pragma unroll
    for (int n = 0; n < 8; ++n) {
        const float s = ldsc[0][n][tid] + ldsc[1][n][tid] + ldsc[2][n][tid] + ldsc[3][n][tid];
        chan_part[((size_t)n * 2048 + bid) * C_ + tid] = s;
    }
    if (tid < 8)
        smax_part[tid * 2048 + bid] =
            fmaxf(fmaxf(wmax[0][tid], wmax[1][tid]), fmaxf(wmax[2][tid], wmax[3][tid]));
}

// K2: 256 blocks = (n, sub 0..31) — PARTITIONED, nothing redundant (round-4
// lesson: 64-block full-recompute was 114us latency-bound). Each block: full
// spatial max (cheap, 2048 reads); sden partial over 512 rows; bg partial over
// 512 rows; channel partial over 64 chunks. All deterministic writes.
__global__ __launch_bounds__(256) void k_soft(const float* __restrict__ fea_sum,
                                              const float* __restrict__ chan_part,
                                              const float* __restrict__ smax_part,
                                              const float* __restrict__ gt,
                                              float* __restrict__ sden_part,  // [N][32]
                                              float* __restrict__ bg_part,    // [N][32]
                                              float* __restrict__ chan_sub,   // [N][32][C]
                                              float* __restrict__ stats) {    // [N] = sm
    const int n   = blockIdx.x >> 5;
    const int sub = blockIdx.x & 31;
    const int tid = threadIdx.x;
    __shared__ float red[256];
    __shared__ int   bb[NB_][4];

    if (tid < NB_) {
        const float* bx = gt + ((size_t)n * NB_ + tid) * 4;
        bb[tid][0] = (int)floorf(bx[0] / IMG_W * (float)W_);
        bb[tid][1] = (int)ceilf (bx[2] / IMG_W * (float)W_);
        bb[tid][2] = (int)floorf(bx[1] / IMG_H * (float)H_);
        bb[tid][3] = (int)ceilf (bx[3] / IMG_H * (float)H_);
    }

    // ---- spatial max over 2048 chunk maxes
    float m = -1e30f;
    #pragma unroll
    for (int k = 0; k < 8; ++k) m = fmaxf(m, smax_part[n * 2048 + k * 256 + tid]);
    red[tid] = m; __syncthreads();
    for (int s = 128; s > 0; s >>= 1) { if (tid < s) red[tid] = fmaxf(red[tid], red[tid + s]); __syncthreads(); }
    const float sm = red[0] * (1.0f / (C_ * TEMP));
    __syncthreads();

    // ---- sden partial over rows [sub*512, +512)
    float acc = 0.f;
    #pragma unroll
    for (int k = 0; k < 2; ++k)
        acc += expf(fea_sum[n * HW_ + sub * 512 + k * 256 + tid] * (1.0f / (C_ * TEMP)) - sm);
    red[tid] = acc; __syncthreads();
    for (int s = 128; s > 0; s >>= 1) { if (tid < s) red[tid] += red[tid + s]; __syncthreads(); }
    if (tid == 0) sden_part[n * 32 + sub] = red[0];
    __syncthreads();

    // ---- bg partial over the same 512 rows
    float cnt = 0.f;
    #pragma unroll
    for (int k = 0; k < 2; ++k) {
        const int i = sub * 512 + k * 256 + tid;
        const int h = i >> 7, w = i & 127;
        bool in = false;
        for (int b = 0; b < NB_; ++b)
            in = in || (h >= bb[b][2] && h <= bb[b][3] && w >= bb[b][0] && w <= bb[b][1]);
        cnt += in ? 0.f : 1.f;
    }
    red[tid] = cnt; __syncthreads();
    for (int s = 128; s > 0; s >>= 1) { if (tid < s) red[tid] += red[tid + s]; __syncthreads(); }
    if (tid == 0) bg_part[n * 32 + sub] = red[0];
    if (tid == 0 && sub == 0) stats[n] = sm;

    // ---- channel partial over chunks [sub*64, +64)
    float cs = 0.f;
    #pragma unroll 4
    for (int k = 0; k < 64; ++k)
        cs += chan_part[((size_t)n * 2048 + sub * 64 + k) * C_ + tid];
    chan_sub[((size_t)n * 32 + sub) * C_ + tid] = cs;
}

// K2b: 64 blocks = (n, sub 0..7). Fixed-order combine of the 32 partials
// (deterministic); fg recomputed from LDS boxes (validated in round 4);
// writes A_t[hw*8+n] (transposed for k_main). sub==0 also computes B.
__global__ __launch_bounds__(256) void k_A(const float* __restrict__ fea_sum,
                                           const float* __restrict__ gt,
                                           const float* __restrict__ sden_part,
                                           const float* __restrict__ bg_part,
                                           const float* __restrict__ stats,
                                           const float* __restrict__ chan_sub,
                                           float* __restrict__ A_t,   // [HW][8]
                                           float* __restrict__ B) {
    const int n   = blockIdx.x >> 3;
    const int sub = blockIdx.x & 7;
    const int tid = threadIdx.x;
    __shared__ int   bb[NB_][4];
    __shared__ float barea[NB_];
    __shared__ float red[256];

    if (tid < NB_) {
        const float* bx = gt + ((size_t)n * NB_ + tid) * 4;
        const int wmin = (int)floorf(bx[0] / IMG_W * (float)W_);
        const int wmax = (int)ceilf (bx[2] / IMG_W * (float)W_);
        const int hmin = (int)floorf(bx[1] / IMG_H * (float)H_);
        const int hmax = (int)ceilf (bx[3] / IMG_H * (float)H_);
        bb[tid][0] = wmin; bb[tid][1] = wmax; bb[tid][2] = hmin; bb[tid][3] = hmax;
        barea[tid] = 1.0f / (float)(hmax + 1 - hmin) / (float)(wmax + 1 - wmin);
    }
    const float sm = stats[n];
    float sden = 0.f, bgs = 0.f;
    #pragma unroll
    for (int j = 0; j < 32; ++j) { sden += sden_part[n * 32 + j]; bgs += bg_part[n * 32 + j]; }
    const float bginv = (bgs > 0.f) ? 1.0f / bgs : 1.0f;
    __syncthreads();

    #pragma unroll
    for (int k = 0; k < 8; ++k) {
        const int i = sub * 2048 + k * 256 + tid;
        const int h = i >> 7, w = i & 127;
        float fg = 0.f;
        for (int b = 0; b < NB_; ++b)
            if (h >= bb[b][2] && h <= bb[b][3] && w >= bb[b][0] && w <= bb[b][1])
                fg = fmaxf(fg, barea[b]);
        const float S_att = (float)HW_ * expf(fea_sum[n * HW_ + i] * (1.0f / (C_ * TEMP)) - sm) / sden;
        const float bg = (fg <= 0.f) ? bginv : 0.f;
        A_t[(size_t)i * 8 + n] = sqrtf(S_att) * (sqrtf(fg) + sqrtf(bg)) * (1.0f / (float)HW_);
    }

    if (sub != 0) return;   // block-uniform exit
    __syncthreads();
    float cs = 0.f;
    #pragma unroll
    for (int s = 0; s < 32; ++s)
        cs += chan_sub[((size_t)n * 32 + s) * C_ + tid];
    const float lc = cs * (1.0f / (HW_ * TEMP));
    red[tid] = lc; __syncthreads();
    for (int s = 128; s > 0; s >>= 1) { if (tid < s) red[tid] = fmaxf(red[tid], red[tid + s]); __syncthreads(); }
    const float cmax = red[0]; __syncthreads();
    const float e = expf(lc - cmax);
    red[tid] = e; __syncthreads();
    for (int s = 128; s > 0; s >>= 1) { if (tid < s) red[tid] += red[tid + s]; __syncthreads(); }
    B[n * C_ + tid] = sqrtf((float)C_ * e / red[0]);   // sqrt(C_att)
}

// K3: main weighted-L1 reduction — proven round-4 form (contiguous 32KB tiles,
// ~7 TB/s). Wave = one hw, all 8 n; B staged in LDS; A_t row is one cacheline;
// pS non-temporal. grid: 4096 x 256.
__global__ __launch_bounds__(256, 4) void k_main(const float* __restrict__ pS,
                                                 const float* __restrict__ pT,
                                                 const float* __restrict__ A_t,
                                                 const float* __restrict__ B,
                                                 float* __restrict__ partials) {
    __shared__ float4 ldsB[512];
    const int tid = threadIdx.x;
    ldsB[tid]       = ((const float4*)B)[tid];
    ldsB[tid + 256] = ((const float4*)B)[tid + 256];
    __syncthreads();

    const int wave = tid >> 6, lane = tid & 63;
    const int hw   = blockIdx.x * 4 + wave;
    float a[8];
    #pragma unroll
    for (int j = 0; j < 8; ++j) a[j] = A_t[(size_t)hw * 8 + j];

    const size_t base4 = (size_t)hw * 512 + lane;
    f4 sv[8], tv[8];
    #pragma unroll
    for (int j = 0; j < 8; ++j) {
        sv[j] = __builtin_nontemporal_load((const f4*)pS + base4 + (size_t)j * 64);
        tv[j] = *((const f4*)pT + base4 + (size_t)j * 64);
    }
    float acc = 0.f;
    #pragma unroll
    for (int j = 0; j < 8; ++j) {
        const float4 b4 = ldsB[j * 64 + lane];
        const float part = fabsf(sv[j].x - tv[j].x) * b4.x + fabsf(sv[j].y - tv[j].y) * b4.y +
                           fabsf(sv[j].z - tv[j].z) * b4.z + fabsf(sv[j].w - tv[j].w) * b4.w;
        acc += a[j] * part;
    }
    acc = waveReduceSum(acc);
    __shared__ float red[4];
    if (lane == 0) red[wave] = acc;
    __syncthreads();
    if (tid == 0) partials[blockIdx.x] = red[0] + red[1] + red[2] + red[3];
}

// K4: deterministic finalize: sum 4096 block partials -> d_out[0]
__global__ __launch_bounds__(256) void k_final(const float* __restrict__ partials,
                                               float* __restrict__ out) {
    float a = 0.f;
    for (int i = threadIdx.x; i < 4096; i += 256) a += partials[i];
    __shared__ float red[256];
    red[threadIdx.x] = a; __syncthreads();
    for (int s = 128; s > 0; s >>= 1) { if (threadIdx.x < s) red[threadIdx.x] += red[threadIdx.x + s]; __syncthreads(); }
    if (threadIdx.x == 0) out[0] = red[0];
}

extern "C" void kernel_launch(void* const* d_in, const int* in_sizes, int n_in,
                              void* d_out, int out_size, void* d_ws, size_t ws_size,
                              hipStream_t stream) {
    const float* pS = (const float*)d_in[0];
    const float* pT = (const float*)d_in[1];
    const float* gt = (const float*)d_in[2];
    float* ws = (float*)d_ws;

    // workspace layout (floats) — no atomics, no memset. ~18.2 MB total.
    float* chan_part = ws;                        // 4194304 = N*2048*C
    float* smax_part = chan_part + 4194304;       // 16384   = N*2048
    float* sden_part = smax_part + 16384;         // 256     = N*32
    float* bg_part   = sden_part + 256;           // 256
    float* stats     = bg_part + 256;             // 16
    float* chan_sub  = stats + 16;                // 65536   = N*32*C
    float* fea_sum   = chan_sub + 65536;          // 131072
    float* A_t       = fea_sum + 131072;          // 131072  = HW*8
    float* B         = A_t + 131072;              // 2048    (16B aligned)
    float* partials  = B + 2048;                  // 4096

    k_stats<<<2048, 256, 0, stream>>>(pT, chan_part, fea_sum, smax_part);
    k_soft <<<256,  256, 0, stream>>>(fea_sum, chan_part, smax_part, gt,
                                      sden_part, bg_part, chan_sub, stats);
    k_A    <<<64,   256, 0, stream>>>(fea_sum, gt, sden_part, bg_part, stats,
                                      chan_sub, A_t, B);
    k_main <<<4096, 256, 0, stream>>>(pS, pT, A_t, B, partials);
    k_final<<<1,    256, 0, stream>>>(partials, (float*)d_out);
}